// Round 4
// baseline (129.531 us; speedup 1.0000x reference)
//
#include <hip/hip_runtime.h>

// STFT round-trip collapse:
//   conc == ft                      (mag/phase identity: mag*cos(atan2(i,r)) = r, etc.)
//   fwd composed with inv == diag(win)/SCALE   (pinv(fb)@fb = I; fb is 1026x1024 full column rank)
//   => out[b,u] = wav[b,u] * W1[u+PAD] / (EPS + W2[u+PAD])
// where W1/W2 sum win / win^2 over the <=4 frames overlapping padded sample t=u+PAD.
// Reflect padding only influences samples cropped by y[:, PAD:-PAD]. Pure streaming kernel.

constexpr int kCols     = 2097152;   // T
constexpr int kHop      = 256;
constexpr int kPad      = 512;       // FILTER_LENGTH/2
constexpr int kMaxFrame = 8192;      // nF - 1

__global__ __launch_bounds__(256) void stft_roundtrip_kernel(
    const float* __restrict__ wav,
    const float* __restrict__ sqw,   // square_window = win^2, 1024 floats
    float* __restrict__ out,
    int batch)
{
    const int tid = blockIdx.x * blockDim.x + threadIdx.x;
    const int u0 = tid * 4;
    if (u0 >= kCols) return;

    // Per-column gain = W1 / (EPS + W2), from the actual square_window input.
    float g[4];
#pragma unroll
    for (int q = 0; q < 4; ++q) {
        const int t   = u0 + q + kPad;
        const int fhi = t >> 8;        // highest candidate frame index
        const int m   = t & 255;       // window offset phase
        float w1 = 0.0f, w2 = 0.0f;
#pragma unroll
        for (int j = 0; j < 4; ++j) {
            const int f = fhi - j;     // frame index; window pos k = m + 256*j in [0,1024)
            if (f >= 0 && f <= kMaxFrame) {
                const float s = sqw[m + kHop * j];
                w2 += s;
                w1 += sqrtf(s);        // win[k] >= 0 (Hann)
            }
        }
        g[q] = w1 / (1e-9f + w2);
    }

    // Apply gain to all batch rows (gain amortized; fully coalesced float4).
    const float4* src = (const float4*)wav;
    float4*       dst = (float4*)out;
    const size_t row4 = (size_t)kCols / 4;   // float4 elements per row
    for (int b = 0; b < batch; ++b) {
        const size_t idx = (size_t)b * row4 + (size_t)tid;
        float4 v = src[idx];
        v.x *= g[0];
        v.y *= g[1];
        v.z *= g[2];
        v.w *= g[3];
        dst[idx] = v;
    }
}

extern "C" void kernel_launch(void* const* d_in, const int* in_sizes, int n_in,
                              void* d_out, int out_size, void* d_ws, size_t ws_size,
                              hipStream_t stream)
{
    const float* wav = (const float*)d_in[0];   // (B, 2097152) f32
    const float* sqw = (const float*)d_in[3];   // (1024,) f32
    float* out = (float*)d_out;                 // (B, 2097152) f32

    const int batch = in_sizes[0] / kCols;      // 8
    const int threads  = 256;
    const int total_thr = kCols / 4;                       // one float4 column group per thread
    const int blocks   = (total_thr + threads - 1) / threads;  // 2048
    stft_roundtrip_kernel<<<blocks, threads, 0, stream>>>(wav, sqw, out, batch);
}